// Round 12
// baseline (1391.509 us; speedup 1.0000x reference)
//
#include <hip/hip_runtime.h>
#include <math.h>

// B=16, N=256, H=1024, HID=300, HID1=301 (pad 304), L=64, M=B*N=4096
// Biaffine GEMMs: split-bf16 MFMA, 3-term hi/lo (ah*bh + al*bh + ah*bl),
// K' = 912 padded to 120 chunks (15 iters), double-buffered LDS (single
// barrier/iter: loads for iter+1 fly during iter's MFMAs).
// CRF kernels SEPARATE (R10 fusion pushed Ec[64] to scratch, 2x slower).

typedef short bf16x8 __attribute__((ext_vector_type(8)));
typedef float f32x4 __attribute__((ext_vector_type(4)));

__device__ __forceinline__ float rlf(float v, int l) {
    return __uint_as_float(__builtin_amdgcn_readlane(__float_as_uint(v), (unsigned)l));
}
__device__ __forceinline__ int rli(int v, int l) {
    return __builtin_amdgcn_readlane(v, (unsigned)l);
}
__device__ __forceinline__ unsigned short f2bf(float x) {
    union { float f; unsigned u; } c; c.f = x;
    unsigned r = c.u + 0x7FFF + ((c.u >> 16) & 1);
    return (unsigned short)(r >> 16);
}
__device__ __forceinline__ float bf2f(unsigned short h) {
    union { unsigned u; float f; } c; c.u = ((unsigned)h) << 16; return c.f;
}
__device__ __forceinline__ void gload16(const void* g, const void* lds) {
    __builtin_amdgcn_global_load_lds(
        (const __attribute__((address_space(1))) void*)g,
        (__attribute__((address_space(3))) void*)lds, 16, 0, 0);
}

// ---------------------------------------------------------------------------
__global__ void mask_cvt_kernel(const void* __restrict__ mraw, int* __restrict__ maskI,
                                int* __restrict__ lenB, int* __restrict__ zbuf) {
    int b = blockIdx.x, t = threadIdx.x;
    if (b == 0 && t < 8) zbuf[t] = 0;
    int i = b * 256 + t;
    unsigned int w0 = ((const unsigned int*)mraw)[0];
    int v;
    if (w0 == 1u)               v = ((const int*)mraw)[i];
    else if (w0 == 0x3F800000u) v = (((const float*)mraw)[i] != 0.f) ? 1 : 0;
    else                        v = ((const unsigned char*)mraw)[i] ? 1 : 0;
    maskI[i] = v;
    __shared__ int sh[4];
    int s = v;
    #pragma unroll
    for (int m = 32; m; m >>= 1) s += __shfl_xor(s, m);
    if ((t & 63) == 0) sh[t >> 6] = s;
    __syncthreads();
    if (t == 0) lenB[b] = sh[0] + sh[1] + sh[2] + sh[3];
}

// ---------------------------------------------------------------------------
__global__ __launch_bounds__(256)
void wsplit_kernel(const float* __restrict__ Wbil,
                   unsigned short* __restrict__ Wbh, unsigned short* __restrict__ Wbl) {
    __shared__ float Tile[304][17];
    const int l = blockIdx.x, jt = blockIdx.y, t = threadIdx.x;
    const int j0 = jt * 16;
    {
        int jj = t & 15, it = t >> 4;
        #pragma unroll
        for (int ib = 0; ib < 19; ++ib) {
            int i = ib * 16 + it;
            float v = 0.f;
            if (i < 301 && j0 + jj < 301)
                v = Wbil[(size_t)l * 90601 + (size_t)i * 301 + j0 + jj];
            Tile[i][jj] = v;
        }
    }
    __syncthreads();
    {
        int il = t & 15, jj = t >> 4;
        #pragma unroll
        for (int ib = 0; ib < 19; ++ib) {
            int i = ib * 16 + il;
            float v = Tile[i][jj];
            unsigned short hi = f2bf(v);
            unsigned short lo = f2bf(v - bf2f(hi));
            size_t o = ((size_t)(l * 304 + j0 + jj)) * 304 + i;
            Wbh[o] = hi; Wbl[o] = lo;
        }
    }
}

// ---------------------------------------------------------------------------
__global__ __launch_bounds__(256)
void mlp_kernel(const float* __restrict__ A,
                const float* __restrict__ Wh, const float* __restrict__ bh_,
                const float* __restrict__ Wd, const float* __restrict__ bd_,
                unsigned short* __restrict__ h1h, unsigned short* __restrict__ h1l,
                unsigned short* __restrict__ d1h, unsigned short* __restrict__ d1l) {
    constexpr int BM = 128, BN = 128, BK = 16;
    __shared__ float As[BK][BM + 4];
    __shared__ float Bs[BK][BN + 4];

    const int t = threadIdx.x;
    const int tn = t & 15, tm = t >> 4;
    const size_t a_row0 = (size_t)blockIdx.x * BM;
    const int n0 = blockIdx.y * BN;
    const int z = blockIdx.z;
    const float* Bm = z ? Wd : Wh;
    const float* bias = z ? bd_ : bh_;
    unsigned short* Ch = z ? d1h : h1h;
    unsigned short* Cl = z ? d1l : h1l;

    float acc[2][2][4][4] = {};
    const int ar = t >> 2, ak = (t & 3) * 4;

    for (int k0 = 0; k0 < 1024; k0 += BK) {
        {
            const float* ap = A + (a_row0 + ar) * 1024 + k0 + ak;
            float4 v0 = *(const float4*)ap;
            float4 v1 = *(const float4*)(ap + 64 * 1024);
            As[ak + 0][ar] = v0.x; As[ak + 1][ar] = v0.y;
            As[ak + 2][ar] = v0.z; As[ak + 3][ar] = v0.w;
            As[ak + 0][64 + ar] = v1.x; As[ak + 1][64 + ar] = v1.y;
            As[ak + 2][64 + ar] = v1.z; As[ak + 3][64 + ar] = v1.w;
        }
        {
            int r1 = min(n0 + ar, 299), r2 = min(n0 + 64 + ar, 299);
            const float* q1 = Bm + (size_t)r1 * 1024 + k0 + ak;
            const float* q2 = Bm + (size_t)r2 * 1024 + k0 + ak;
            float4 v0 = *(const float4*)q1;
            float4 v1 = *(const float4*)q2;
            Bs[ak + 0][ar] = v0.x; Bs[ak + 1][ar] = v0.y;
            Bs[ak + 2][ar] = v0.z; Bs[ak + 3][ar] = v0.w;
            Bs[ak + 0][64 + ar] = v1.x; Bs[ak + 1][64 + ar] = v1.y;
            Bs[ak + 2][64 + ar] = v1.z; Bs[ak + 3][64 + ar] = v1.w;
        }
        __syncthreads();
        #pragma unroll
        for (int kk = 0; kk < BK; ++kk) {
            float4 a0 = *(const float4*)&As[kk][tm * 4];
            float4 a1 = *(const float4*)&As[kk][64 + tm * 4];
            float4 b0 = *(const float4*)&Bs[kk][tn * 4];
            float4 b1 = *(const float4*)&Bs[kk][64 + tn * 4];
            float av[2][4] = {{a0.x, a0.y, a0.z, a0.w}, {a1.x, a1.y, a1.z, a1.w}};
            float bv[2][4] = {{b0.x, b0.y, b0.z, b0.w}, {b1.x, b1.y, b1.z, b1.w}};
            #pragma unroll
            for (int ih = 0; ih < 2; ++ih)
                #pragma unroll
                for (int ii = 0; ii < 4; ++ii)
                    #pragma unroll
                    for (int jh = 0; jh < 2; ++jh)
                        #pragma unroll
                        for (int jj = 0; jj < 4; ++jj)
                            acc[ih][jh][ii][jj] =
                                fmaf(av[ih][ii], bv[jh][jj], acc[ih][jh][ii][jj]);
        }
        __syncthreads();
    }

    #pragma unroll
    for (int ih = 0; ih < 2; ++ih) {
        #pragma unroll
        for (int ii = 0; ii < 4; ++ii) {
            int r = ih * 64 + tm * 4 + ii;
            #pragma unroll
            for (int jh = 0; jh < 2; ++jh) {
                int n = n0 + jh * 64 + tn * 4;
                if (n < 304) {
                    float o[4];
                    #pragma unroll
                    for (int q = 0; q < 4; ++q) {
                        int nq = n + q;
                        float v = acc[ih][jh][ii][q];
                        o[q] = (nq < 300) ? fmaxf(v + bias[min(nq, 299)], 0.f)
                                          : ((nq == 300) ? 1.f : 0.f);
                    }
                    ushort4 h4, l4;
                    h4.x = f2bf(o[0]); l4.x = f2bf(o[0] - bf2f(h4.x));
                    h4.y = f2bf(o[1]); l4.y = f2bf(o[1] - bf2f(h4.y));
                    h4.z = f2bf(o[2]); l4.z = f2bf(o[2] - bf2f(h4.z));
                    h4.w = f2bf(o[3]); l4.w = f2bf(o[3] - bf2f(h4.w));
                    size_t base = (a_row0 + r) * 304 + n;
                    *(ushort4*)&Ch[base] = h4;
                    *(ushort4*)&Cl[base] = l4;
                }
            }
        }
    }
}

// ---------------------------------------------------------------------------
// Split-bf16 MFMA GEMM, 3-term, DOUBLE-BUFFERED LDS (one barrier/iter).
// MODE 1: U' = d1 x Wb; MODE 2: s = h1 x U'.
// ---------------------------------------------------------------------------
template <int MODE>
__global__ __launch_bounds__(256)
void gemm_mfma(const unsigned short* __restrict__ Ah, const unsigned short* __restrict__ Al,
               const unsigned short* __restrict__ Bh, const unsigned short* __restrict__ Bl,
               float* __restrict__ outF, unsigned short* __restrict__ outUh,
               unsigned short* __restrict__ outUl, const unsigned short* __restrict__ zbuf,
               int c0) {
    __shared__ short Als[2][128 * 64];
    __shared__ short Bls[2][128 * 64];

    const int t = threadIdx.x;
    const int lane = t & 63;
    const int w = t >> 6, wr = w >> 1, wc = w & 1;
    const int bx = blockIdx.x, n0 = blockIdx.y * 128;

    int arow0;
    if constexpr (MODE == 1) {
        arow0 = c0 * 256 + bx * 128;
    } else {
        arow0 = (c0 + blockIdx.z) * 256 + bx * 128;
    }

    int kcd[4];
    size_t rowA[4], rowB[4];
    int wbase[4];
    #pragma unroll
    for (int c4 = 0; c4 < 4; ++c4) {
        int ch = c4 * 256 + t;
        int r = ch >> 3;
        kcd[c4] = (ch & 7) ^ (r & 7);
        rowA[c4] = (size_t)(arow0 + r) * 304;
        if constexpr (MODE == 1) {
            rowB[c4] = (size_t)(n0 + r) * 304;
        } else {
            int rb = n0 + r;
            rowB[c4] = (size_t)(blockIdx.z * 256 + (rb >> 6)) * 19456 +
                       (size_t)(rb & 63) * 304;
        }
        wbase[c4] = (c4 * 256 + (t & ~63)) * 8;
    }

    f32x4 acc[4][4];
    #pragma unroll
    for (int i = 0; i < 4; ++i)
        #pragma unroll
        for (int j = 0; j < 4; ++j)
            acc[i][j] = (f32x4){0.f, 0.f, 0.f, 0.f};

    const int rowA_l = wr * 64 + (lane & 15);
    const int rowB_l = wc * 64 + (lane & 15);
    const int csub = lane >> 4;
    const int cxor = lane & 7;

    // stage(it, buf): issue the 8 global_load_lds for K-iter `it` into buf
    auto stage = [&](int it, int buf) {
        const int it8 = it * 8;
        #pragma unroll
        for (int c4 = 0; c4 < 4; ++c4) {
            int kg = it8 + kcd[c4];
            {
                const unsigned short* sa;
                if (kg < 38)       sa = Ah + rowA[c4] + (size_t)kg * 8;
                else if (kg < 76)  sa = Al + rowA[c4] + (size_t)(kg - 38) * 8;
                else if (kg < 114) sa = Ah + rowA[c4] + (size_t)(kg - 76) * 8;
                else               sa = zbuf;
                gload16(sa, &Als[buf][wbase[c4]]);
            }
            {
                const unsigned short* sb;
                if (kg < 38)       sb = Bh + rowB[c4] + (size_t)kg * 8;
                else if (kg < 76)  sb = Bh + rowB[c4] + (size_t)(kg - 38) * 8;
                else if (kg < 114) sb = Bl + rowB[c4] + (size_t)(kg - 76) * 8;
                else               sb = zbuf;
                gload16(sb, &Bls[buf][wbase[c4]]);
            }
        }
    };

    stage(0, 0);
    __syncthreads();   // vmcnt(0) drain: buf0 ready

    for (int it = 0; it < 15; ++it) {
        const int cur = it & 1;
        if (it + 1 < 15) stage(it + 1, cur ^ 1);   // loads fly during MFMAs

        #pragma unroll
        for (int kh = 0; kh < 2; ++kh) {
            const int kcr = ((kh * 4 + csub) ^ cxor) * 8;
            bf16x8 af[4], bfr[4];
            #pragma unroll
            for (int f = 0; f < 4; ++f)
                af[f] = *(const bf16x8*)&Als[cur][(rowA_l + f * 16) * 64 + kcr];
            #pragma unroll
            for (int f = 0; f < 4; ++f)
                bfr[f] = *(const bf16x8*)&Bls[cur][(rowB_l + f * 16) * 64 + kcr];
            #pragma unroll
            for (int fr = 0; fr < 4; ++fr)
                #pragma unroll
                for (int fb = 0; fb < 4; ++fb)
                    acc[fr][fb] = __builtin_amdgcn_mfma_f32_16x16x32_bf16(
                        af[fr], bfr[fb], acc[fr][fb], 0, 0, 0);
        }
        // one barrier per iter: (a) next buf's loads drained (vmcnt0 at
        // barrier), (b) all waves done reading cur before it's overwritten.
        __syncthreads();
    }

    const int mbase = bx * 128 + wr * 64 + ((lane >> 4) << 2);
    const int nbase = n0 + wc * 64 + (lane & 15);
    #pragma unroll
    for (int fb = 0; fb < 4; ++fb) {
        const int n = nbase + fb * 16;
        if constexpr (MODE == 1) {
            #pragma unroll
            for (int fr = 0; fr < 4; ++fr) {
                #pragma unroll
                for (int reg = 0; reg < 4; ++reg) {
                    int xloc = mbase + fr * 16 + reg;
                    float v = acc[fr][fb][reg];
                    unsigned short hi = f2bf(v);
                    unsigned short lo = f2bf(v - bf2f(hi));
                    size_t o = (size_t)xloc * 19456 + n;
                    outUh[o] = hi;
                    outUl[o] = lo;
                }
            }
        } else {
            const int xx = n >> 6, lt = n & 63;
            const size_t sbase = (size_t)(c0 + blockIdx.z) * 4194304 +
                                 (size_t)xx * 16384 + lt;
            #pragma unroll
            for (int fr = 0; fr < 4; ++fr) {
                #pragma unroll
                for (int reg = 0; reg < 4; ++reg) {
                    int y = mbase + fr * 16 + reg;
                    outF[sbase + (size_t)y * 64] = acc[fr][fb][reg];
                }
            }
        }
    }
}

// ---------------------------------------------------------------------------
// Forward CRF (num - den); softmax cancels. Masked rows skipped.
// ---------------------------------------------------------------------------
__global__ __launch_bounds__(256, 4)
void fwd_kernel(const float* __restrict__ s_flat, const int* __restrict__ lenB,
                const int* __restrict__ maskI, const int* __restrict__ labels,
                const float* __restrict__ trans, const float* __restrict__ start_trans,
                const float* __restrict__ end_trans, float* __restrict__ rowterm) {
    __shared__ float T[4096];
    const int t = threadIdx.x;
    for (int i = t; i < 4096; i += 256) T[i] = trans[i];
    __syncthreads();

    const int lane = t & 63, wid = t >> 6;
    const int row = blockIdx.x * 4 + wid;
    if (maskI[row] == 0) {
        if (lane == 0) rowterm[row] = 0.f;
        return;
    }
    const int len = lenB[row >> 8];
    const float* srow = s_flat + (size_t)row * 16384;
    const int* lrow = labels + (size_t)row * 256;

    float Ec[64];
    #pragma unroll
    for (int p = 0; p < 64; ++p) Ec[p] = __expf(T[p * 64 + lane]);

    const float et = end_trans[lane];

    float sv = srow[lane];
    int tagprev = lrow[0];
    float num = start_trans[tagprev] + rlf(sv, tagprev);
    float alpha = start_trans[lane] + sv;
    float sv_pre = srow[64 + lane];

    for (int y = 1; y < len; ++y) {
        sv = sv_pre;
        int ynext = (y + 1 < len) ? (y + 1) : (len - 1);
        sv_pre = srow[ynext * 64 + lane];

        const int tag = lrow[y];
        num += rlf(sv, tag) + T[tagprev * 64 + tag];
        tagprev = tag;

        float am = alpha;
        #pragma unroll
        for (int m = 32; m; m >>= 1) am = fmaxf(am, __shfl_xor(am, m));
        float ea = __expf(alpha - am);
        float a0 = 0.f, a1 = 0.f, a2 = 0.f, a3 = 0.f;
        #pragma unroll
        for (int p = 0; p < 64; p += 4) {
            a0 = fmaf(rlf(ea, p + 0), Ec[p + 0], a0);
            a1 = fmaf(rlf(ea, p + 1), Ec[p + 1], a1);
            a2 = fmaf(rlf(ea, p + 2), Ec[p + 2], a2);
            a3 = fmaf(rlf(ea, p + 3), Ec[p + 3], a3);
        }
        alpha = am + __logf((a0 + a1) + (a2 + a3)) + sv;
    }

    num += end_trans[tagprev];
    float da = alpha + et;
    float dmx = da;
    #pragma unroll
    for (int m = 32; m; m >>= 1) dmx = fmaxf(dmx, __shfl_xor(dmx, m));
    float ds = __expf(da - dmx);
    #pragma unroll
    for (int m = 32; m; m >>= 1) ds += __shfl_xor(ds, m);
    float den = dmx + __logf(ds);
    if (lane == 0) rowterm[row] = num - den;
}

// ---------------------------------------------------------------------------
// Viterbi forward, max-only. Stores vs state per step.
// ---------------------------------------------------------------------------
__global__ __launch_bounds__(256, 4)
void vitf_kernel(const float* __restrict__ s_flat, const int* __restrict__ lenB,
                 const float* __restrict__ trans, const float* __restrict__ start_trans,
                 const float* __restrict__ end_trans, float* __restrict__ vsb,
                 float* __restrict__ decoded) {
    const int t = threadIdx.x;
    const int lane = t & 63, wid = t >> 6;
    const int row = blockIdx.x * 4 + wid;
    const int len = lenB[row >> 8];
    const float* srow = s_flat + (size_t)row * 16384;
    float* vrow = vsb + (size_t)row * 16384;

    float sv = srow[lane];
    float vs = start_trans[lane] + sv;
    float sv_pre = srow[64 + lane];

    for (int y = 1; y < len; ++y) {
        vrow[(y - 1) * 64 + lane] = vs;
        float svc = sv_pre;
        int ynext = (y + 1 < len) ? (y + 1) : (len - 1);
        sv_pre = srow[ynext * 64 + lane];

        float m0 = -3.4e38f, m1 = -3.4e38f, m2 = -3.4e38f, m3 = -3.4e38f;
        #pragma unroll
        for (int p = 0; p < 64; p += 8) {
            float t0 = rlf(vs, p + 0) + trans[(p + 0) * 64 + lane];
            float t1 = rlf(vs, p + 1) + trans[(p + 1) * 64 + lane];
            m0 = fmaxf(fmaxf(t0, t1), m0);
            float t2 = rlf(vs, p + 2) + trans[(p + 2) * 64 + lane];
            float t3 = rlf(vs, p + 3) + trans[(p + 3) * 64 + lane];
            m1 = fmaxf(fmaxf(t2, t3), m1);
            float t4 = rlf(vs, p + 4) + trans[(p + 4) * 64 + lane];
            float t5 = rlf(vs, p + 5) + trans[(p + 5) * 64 + lane];
            m2 = fmaxf(fmaxf(t4, t5), m2);
            float t6 = rlf(vs, p + 6) + trans[(p + 6) * 64 + lane];
            float t7 = rlf(vs, p + 7) + trans[(p + 7) * 64 + lane];
            m3 = fmaxf(fmaxf(t6, t7), m3);
        }
        vs = fmaxf(fmaxf(m0, m1), fmaxf(m2, m3)) + svc;
    }

    float fe = vs + end_trans[lane];
    float mx = fe;
    #pragma unroll
    for (int m = 32; m; m >>= 1) mx = fmaxf(mx, __shfl_xor(mx, m));
    unsigned long long msk = __ballot(fe == mx);
    int fi = (int)__builtin_ctzll(msk);

    if (lane == 0) decoded[(size_t)row * 256 + 255] = (float)fi;
}

// ---------------------------------------------------------------------------
// Viterbi backward: recompute argmax per step from stored vs state.
// ---------------------------------------------------------------------------
__global__ __launch_bounds__(256)
void vitb_kernel(const float* __restrict__ vsb, const int* __restrict__ lenB,
                 const float* __restrict__ trans, float* __restrict__ decoded) {
    __shared__ float Tt[64][65];
    const int t = threadIdx.x;
    for (int i = t; i < 4096; i += 256) {
        int p = i >> 6, c = i & 63;
        Tt[c][p] = trans[i];
    }
    __syncthreads();

    const int lane = t & 63, wid = t >> 6;
    const int row = blockIdx.x * 4 + wid;
    const int len = lenB[row >> 8];
    const float* vrow = vsb + (size_t)row * 16384;
    float* drow = decoded + (size_t)row * 256;

    int cur = (int)drow[255];

    for (int y = len - 1 + lane; y < 255; y += 64) drow[y] = (float)cur;

    float v0 = vrow[(len - 2) * 64 + lane];
    float v1 = (len >= 3) ? vrow[(len - 3) * 64 + lane] : 0.f;

    for (int y = len - 2; y >= 0; --y) {
        float vy = v0;
        v0 = v1;
        v1 = (y >= 2) ? vrow[(y - 2) * 64 + lane] : 0.f;

        float tp = vy + Tt[cur][lane];
        float mx = tp;
        #pragma unroll
        for (int m = 32; m; m >>= 1) mx = fmaxf(mx, __shfl_xor(mx, m));
        unsigned long long msk = __ballot(tp == mx);
        cur = (int)__builtin_ctzll(msk);
        if (lane == 0) drow[y] = (float)cur;
    }
}

// ---------------------------------------------------------------------------
// FALLBACK path (small workspace): hist-based Viterbi + backtrack.
// ---------------------------------------------------------------------------
__global__ __launch_bounds__(256, 3)
void vit_kernel(const float* __restrict__ s_flat, const int* __restrict__ lenB,
                const float* __restrict__ trans, const float* __restrict__ start_trans,
                const float* __restrict__ end_trans, unsigned char* __restrict__ hist,
                float* __restrict__ decoded) {
    const int t = threadIdx.x;
    const int lane = t & 63, wid = t >> 6;
    const int row = blockIdx.x * 4 + wid;
    const int len = lenB[row >> 8];
    const float* srow = s_flat + (size_t)row * 16384;
    unsigned char* hrow = hist + (size_t)row * 16320;

    float sv = srow[lane];
    float vs = start_trans[lane] + sv;
    float sv_pre = srow[64 + lane];

    for (int y = 1; y < len; ++y) {
        sv = sv_pre;
        int ynext = (y + 1 < len) ? (y + 1) : (len - 1);
        sv_pre = srow[ynext * 64 + lane];

        float b0 = -3.4e38f, b1 = -3.4e38f, b2 = -3.4e38f, b3 = -3.4e38f;
        int i0 = 0, i1 = 1, i2 = 2, i3 = 3;
        #pragma unroll
        for (int p = 0; p < 64; p += 4) {
            float t0 = rlf(vs, p + 0) + trans[(p + 0) * 64 + lane]; if (t0 > b0) { b0 = t0; i0 = p + 0; }
            float t1 = rlf(vs, p + 1) + trans[(p + 1) * 64 + lane]; if (t1 > b1) { b1 = t1; i1 = p + 1; }
            float t2 = rlf(vs, p + 2) + trans[(p + 2) * 64 + lane]; if (t2 > b2) { b2 = t2; i2 = p + 2; }
            float t3 = rlf(vs, p + 3) + trans[(p + 3) * 64 + lane]; if (t3 > b3) { b3 = t3; i3 = p + 3; }
        }
        bool c;
        c = (b1 > b0) || (b1 == b0 && i1 < i0);
        float bA = c ? b1 : b0; int iA = c ? i1 : i0;
        c = (b3 > b2) || (b3 == b2 && i3 < i2);
        float bB = c ? b3 : b2; int iB = c ? i3 : i2;
        c = (bB > bA) || (bB == bA && iB < iA);
        float bbv = c ? bB : bA; int bi = c ? iB : iA;

        hrow[(size_t)(y - 1) * 64 + lane] = (unsigned char)bi;
        vs = bbv + sv;
    }

    float fv = vs + end_trans[lane]; int fi = lane;
    #pragma unroll
    for (int m = 32; m; m >>= 1) {
        float ov = __shfl_xor(fv, m);
        int oi = __shfl_xor(fi, m);
        bool cc = (ov > fv) || (ov == fv && oi < fi);
        fv = cc ? ov : fv; fi = cc ? oi : fi;
    }

    if (lane == 0) decoded[(size_t)row * 256 + 255] = (float)fi;
}

__global__ __launch_bounds__(256)
void backtrack_kernel(const unsigned char* __restrict__ hist, const int* __restrict__ lenB,
                      float* __restrict__ decoded) {
    const int lane = threadIdx.x & 63, wid = threadIdx.x >> 6;
    const int row = blockIdx.x * 4 + wid;
    const int len = lenB[row >> 8];
    const unsigned char* hrow = hist + (size_t)row * 16320;
    float* drow = decoded + (size_t)row * 256;

    int cur = (int)drow[255];
    for (int y = len - 1 + lane; y < 255; y += 64) drow[y] = (float)cur;

    int t0 = len - 2;
    int c0 = (int)hrow[(t0 - 0) * 64 + lane];
    int c1 = (int)hrow[(t0 - 1) * 64 + lane];
    int c2 = (int)hrow[(t0 - 2) * 64 + lane];
    int c3 = (int)hrow[(t0 - 3) * 64 + lane];

    for (int y = t0; y >= 0; y -= 4) {
        int yn = y - 4;
        int n0 = 0, n1 = 0, n2 = 0, n3 = 0;
        if (yn - 0 >= 0) n0 = (int)hrow[(yn - 0) * 64 + lane];
        if (yn - 1 >= 0) n1 = (int)hrow[(yn - 1) * 64 + lane];
        if (yn - 2 >= 0) n2 = (int)hrow[(yn - 2) * 64 + lane];
        if (yn - 3 >= 0) n3 = (int)hrow[(yn - 3) * 64 + lane];

        cur = rli(c0, cur);
        if (lane == 0) drow[y] = (float)cur;
        if (y - 1 >= 0) { cur = rli(c1, cur); if (lane == 0) drow[y - 1] = (float)cur; }
        if (y - 2 >= 0) { cur = rli(c2, cur); if (lane == 0) drow[y - 2] = (float)cur; }
        if (y - 3 >= 0) { cur = rli(c3, cur); if (lane == 0) drow[y - 3] = (float)cur; }

        c0 = n0; c1 = n1; c2 = n2; c3 = n3;
    }
}

__global__ void loss_kernel(const float* __restrict__ rowterm, float* __restrict__ out) {
    __shared__ float wsum[4];
    int t = threadIdx.x;
    float s = 0.f;
    for (int i = t; i < 4096; i += 256) s += rowterm[i];
    #pragma unroll
    for (int m = 32; m; m >>= 1) s += __shfl_xor(s, m);
    if ((t & 63) == 0) wsum[t >> 6] = s;
    __syncthreads();
    if (t == 0) out[0] = -(wsum[0] + wsum[1] + wsum[2] + wsum[3]);
}

extern "C" void kernel_launch(void* const* d_in, const int* in_sizes, int n_in,
                              void* d_out, int out_size, void* d_ws, size_t ws_size,
                              hipStream_t stream) {
    const float* input  = (const float*)d_in[0];
    const void*  mraw   = d_in[1];
    const int*   labels = (const int*)d_in[2];
    const float* Wh_in  = (const float*)d_in[3];
    const float* bh     = (const float*)d_in[4];
    const float* Wd_in  = (const float*)d_in[5];
    const float* bd     = (const float*)d_in[6];
    const float* Wbil   = (const float*)d_in[7];
    const float* stt    = (const float*)d_in[8];
    const float* trans  = (const float*)d_in[9];
    const float* ett    = (const float*)d_in[10];

    float* out     = (float*)d_out;
    float* s_flat  = out + 1;
    float* decoded = out + 1 + (size_t)67108864;

    char* ws = (char*)d_ws;
    size_t off = 0;
    unsigned short* h1h = (unsigned short*)(ws + off); off += (size_t)4096 * 304 * 2;
    unsigned short* h1l = (unsigned short*)(ws + off); off += (size_t)4096 * 304 * 2;
    unsigned short* d1h = (unsigned short*)(ws + off); off += (size_t)4096 * 304 * 2;
    unsigned short* d1l = (unsigned short*)(ws + off); off += (size_t)4096 * 304 * 2;
    unsigned short* Wbh = (unsigned short*)(ws + off); off += (size_t)19456 * 304 * 2;
    unsigned short* Wbl = (unsigned short*)(ws + off); off += (size_t)19456 * 304 * 2;
    int* maskI = (int*)(ws + off); off += 16384;
    int* lenB  = (int*)(ws + off); off += 256;
    int* zbuf  = (int*)(ws + off); off += 256;
    float* rowterm = (float*)(ws + off); off += 16384;

    const size_t vsb_bytes = (size_t)4096 * 16384 * 4;
    const size_t hist_bytes = (size_t)4096 * 16320;
    const size_t perb = (size_t)256 * 19456 * 2 * 2;

    bool newpath = (ws_size >= off + vsb_bytes + perb);
    float* vsb = nullptr;
    unsigned char* hist = nullptr;
    if (newpath) { vsb  = (float*)(ws + off); off += vsb_bytes; }
    else         { hist = (unsigned char*)(ws + off); off += hist_bytes; }

    unsigned short* Uh = (unsigned short*)(ws + off);
    size_t avail = (ws_size > off) ? ws_size - off : 0;
    int CB = (int)(avail / perb);
    if (CB < 1) CB = 1;
    if (CB > 16) CB = 16;
    unsigned short* Ul = Uh + (size_t)CB * 256 * 19456;

    mask_cvt_kernel<<<16, 256, 0, stream>>>(mraw, maskI, lenB, zbuf);
    wsplit_kernel<<<dim3(64, 19), 256, 0, stream>>>(Wbil, Wbh, Wbl);
    mlp_kernel<<<dim3(32, 3, 2), 256, 0, stream>>>(input, Wh_in, bh, Wd_in, bd,
                                                   h1h, h1l, d1h, d1l);

    for (int c0 = 0; c0 < 16; c0 += CB) {
        int cb = (CB < 16 - c0) ? CB : (16 - c0);
        gemm_mfma<1><<<dim3(cb * 2, 152), 256, 0, stream>>>(
            d1h, d1l, Wbh, Wbl, nullptr, Uh, Ul, (const unsigned short*)zbuf, c0);
        gemm_mfma<2><<<dim3(2, 128, cb), 256, 0, stream>>>(
            h1h, h1l, Uh, Ul, s_flat, nullptr, nullptr, (const unsigned short*)zbuf, c0);
    }

    fwd_kernel<<<1024, 256, 0, stream>>>(s_flat, lenB, maskI, labels, trans, stt, ett,
                                         rowterm);
    if (newpath) {
        vitf_kernel<<<1024, 256, 0, stream>>>(s_flat, lenB, trans, stt, ett, vsb, decoded);
        vitb_kernel<<<1024, 256, 0, stream>>>(vsb, lenB, trans, decoded);
    } else {
        vit_kernel<<<1024, 256, 0, stream>>>(s_flat, lenB, trans, stt, ett, hist, decoded);
        backtrack_kernel<<<1024, 256, 0, stream>>>(hist, lenB, decoded);
    }
    loss_kernel<<<1, 256, 0, stream>>>(rowterm, out);
}

// Round 13
// 1328.973 us; speedup vs baseline: 1.0471x; 1.0471x over previous
//
#include <hip/hip_runtime.h>
#include <math.h>

// B=16, N=256, H=1024, HID=300, HID1=301 (pad 304), L=64, M=B*N=4096
// Best-measured configuration (R9, 1334 us):
//  - Biaffine GEMMs: split-bf16 MFMA, 3-term hi/lo (ah*bh + al*bh + ah*bl),
//    K' = 912 padded to 120 chunks (15 iters), single-buffer LDS (32KB),
//    U stored [x][19456] natural layout, CB up to 16.
//  - CRF kernels SEPARATE (R10 fusion spilled Ec[64] to scratch, 2x slower).
//  - Viterbi: max-only forward (stores vs state) + backward argmax recompute.
// Falsified levers (do not retry): fwd+vitf fusion (R10), CB<=4 L3-residency
// cap (R11), double-buffered LDS in gemm (R12, occupancy loss > overlap gain).

typedef short bf16x8 __attribute__((ext_vector_type(8)));
typedef float f32x4 __attribute__((ext_vector_type(4)));

__device__ __forceinline__ float rlf(float v, int l) {
    return __uint_as_float(__builtin_amdgcn_readlane(__float_as_uint(v), (unsigned)l));
}
__device__ __forceinline__ int rli(int v, int l) {
    return __builtin_amdgcn_readlane(v, (unsigned)l);
}
__device__ __forceinline__ unsigned short f2bf(float x) {
    union { float f; unsigned u; } c; c.f = x;
    unsigned r = c.u + 0x7FFF + ((c.u >> 16) & 1);
    return (unsigned short)(r >> 16);
}
__device__ __forceinline__ float bf2f(unsigned short h) {
    union { unsigned u; float f; } c; c.u = ((unsigned)h) << 16; return c.f;
}
__device__ __forceinline__ void gload16(const void* g, const void* lds) {
    __builtin_amdgcn_global_load_lds(
        (const __attribute__((address_space(1))) void*)g,
        (__attribute__((address_space(3))) void*)lds, 16, 0, 0);
}

// ---------------------------------------------------------------------------
__global__ void mask_cvt_kernel(const void* __restrict__ mraw, int* __restrict__ maskI,
                                int* __restrict__ lenB, int* __restrict__ zbuf) {
    int b = blockIdx.x, t = threadIdx.x;
    if (b == 0 && t < 8) zbuf[t] = 0;
    int i = b * 256 + t;
    unsigned int w0 = ((const unsigned int*)mraw)[0];
    int v;
    if (w0 == 1u)               v = ((const int*)mraw)[i];
    else if (w0 == 0x3F800000u) v = (((const float*)mraw)[i] != 0.f) ? 1 : 0;
    else                        v = ((const unsigned char*)mraw)[i] ? 1 : 0;
    maskI[i] = v;
    __shared__ int sh[4];
    int s = v;
    #pragma unroll
    for (int m = 32; m; m >>= 1) s += __shfl_xor(s, m);
    if ((t & 63) == 0) sh[t >> 6] = s;
    __syncthreads();
    if (t == 0) lenB[b] = sh[0] + sh[1] + sh[2] + sh[3];
}

// ---------------------------------------------------------------------------
__global__ __launch_bounds__(256)
void wsplit_kernel(const float* __restrict__ Wbil,
                   unsigned short* __restrict__ Wbh, unsigned short* __restrict__ Wbl) {
    __shared__ float Tile[304][17];
    const int l = blockIdx.x, jt = blockIdx.y, t = threadIdx.x;
    const int j0 = jt * 16;
    {
        int jj = t & 15, it = t >> 4;
        #pragma unroll
        for (int ib = 0; ib < 19; ++ib) {
            int i = ib * 16 + it;
            float v = 0.f;
            if (i < 301 && j0 + jj < 301)
                v = Wbil[(size_t)l * 90601 + (size_t)i * 301 + j0 + jj];
            Tile[i][jj] = v;
        }
    }
    __syncthreads();
    {
        int il = t & 15, jj = t >> 4;
        #pragma unroll
        for (int ib = 0; ib < 19; ++ib) {
            int i = ib * 16 + il;
            float v = Tile[i][jj];
            unsigned short hi = f2bf(v);
            unsigned short lo = f2bf(v - bf2f(hi));
            size_t o = ((size_t)(l * 304 + j0 + jj)) * 304 + i;
            Wbh[o] = hi; Wbl[o] = lo;
        }
    }
}

// ---------------------------------------------------------------------------
__global__ __launch_bounds__(256)
void mlp_kernel(const float* __restrict__ A,
                const float* __restrict__ Wh, const float* __restrict__ bh_,
                const float* __restrict__ Wd, const float* __restrict__ bd_,
                unsigned short* __restrict__ h1h, unsigned short* __restrict__ h1l,
                unsigned short* __restrict__ d1h, unsigned short* __restrict__ d1l) {
    constexpr int BM = 128, BN = 128, BK = 16;
    __shared__ float As[BK][BM + 4];
    __shared__ float Bs[BK][BN + 4];

    const int t = threadIdx.x;
    const int tn = t & 15, tm = t >> 4;
    const size_t a_row0 = (size_t)blockIdx.x * BM;
    const int n0 = blockIdx.y * BN;
    const int z = blockIdx.z;
    const float* Bm = z ? Wd : Wh;
    const float* bias = z ? bd_ : bh_;
    unsigned short* Ch = z ? d1h : h1h;
    unsigned short* Cl = z ? d1l : h1l;

    float acc[2][2][4][4] = {};
    const int ar = t >> 2, ak = (t & 3) * 4;

    for (int k0 = 0; k0 < 1024; k0 += BK) {
        {
            const float* ap = A + (a_row0 + ar) * 1024 + k0 + ak;
            float4 v0 = *(const float4*)ap;
            float4 v1 = *(const float4*)(ap + 64 * 1024);
            As[ak + 0][ar] = v0.x; As[ak + 1][ar] = v0.y;
            As[ak + 2][ar] = v0.z; As[ak + 3][ar] = v0.w;
            As[ak + 0][64 + ar] = v1.x; As[ak + 1][64 + ar] = v1.y;
            As[ak + 2][64 + ar] = v1.z; As[ak + 3][64 + ar] = v1.w;
        }
        {
            int r1 = min(n0 + ar, 299), r2 = min(n0 + 64 + ar, 299);
            const float* q1 = Bm + (size_t)r1 * 1024 + k0 + ak;
            const float* q2 = Bm + (size_t)r2 * 1024 + k0 + ak;
            float4 v0 = *(const float4*)q1;
            float4 v1 = *(const float4*)q2;
            Bs[ak + 0][ar] = v0.x; Bs[ak + 1][ar] = v0.y;
            Bs[ak + 2][ar] = v0.z; Bs[ak + 3][ar] = v0.w;
            Bs[ak + 0][64 + ar] = v1.x; Bs[ak + 1][64 + ar] = v1.y;
            Bs[ak + 2][64 + ar] = v1.z; Bs[ak + 3][64 + ar] = v1.w;
        }
        __syncthreads();
        #pragma unroll
        for (int kk = 0; kk < BK; ++kk) {
            float4 a0 = *(const float4*)&As[kk][tm * 4];
            float4 a1 = *(const float4*)&As[kk][64 + tm * 4];
            float4 b0 = *(const float4*)&Bs[kk][tn * 4];
            float4 b1 = *(const float4*)&Bs[kk][64 + tn * 4];
            float av[2][4] = {{a0.x, a0.y, a0.z, a0.w}, {a1.x, a1.y, a1.z, a1.w}};
            float bv[2][4] = {{b0.x, b0.y, b0.z, b0.w}, {b1.x, b1.y, b1.z, b1.w}};
            #pragma unroll
            for (int ih = 0; ih < 2; ++ih)
                #pragma unroll
                for (int ii = 0; ii < 4; ++ii)
                    #pragma unroll
                    for (int jh = 0; jh < 2; ++jh)
                        #pragma unroll
                        for (int jj = 0; jj < 4; ++jj)
                            acc[ih][jh][ii][jj] =
                                fmaf(av[ih][ii], bv[jh][jj], acc[ih][jh][ii][jj]);
        }
        __syncthreads();
    }

    #pragma unroll
    for (int ih = 0; ih < 2; ++ih) {
        #pragma unroll
        for (int ii = 0; ii < 4; ++ii) {
            int r = ih * 64 + tm * 4 + ii;
            #pragma unroll
            for (int jh = 0; jh < 2; ++jh) {
                int n = n0 + jh * 64 + tn * 4;
                if (n < 304) {
                    float o[4];
                    #pragma unroll
                    for (int q = 0; q < 4; ++q) {
                        int nq = n + q;
                        float v = acc[ih][jh][ii][q];
                        o[q] = (nq < 300) ? fmaxf(v + bias[min(nq, 299)], 0.f)
                                          : ((nq == 300) ? 1.f : 0.f);
                    }
                    ushort4 h4, l4;
                    h4.x = f2bf(o[0]); l4.x = f2bf(o[0] - bf2f(h4.x));
                    h4.y = f2bf(o[1]); l4.y = f2bf(o[1] - bf2f(h4.y));
                    h4.z = f2bf(o[2]); l4.z = f2bf(o[2] - bf2f(h4.z));
                    h4.w = f2bf(o[3]); l4.w = f2bf(o[3] - bf2f(h4.w));
                    size_t base = (a_row0 + r) * 304 + n;
                    *(ushort4*)&Ch[base] = h4;
                    *(ushort4*)&Cl[base] = l4;
                }
            }
        }
    }
}

// ---------------------------------------------------------------------------
// Split-bf16 MFMA GEMM, 3-term (K'=912 padded to 960, 15 iters of 64 k').
// MODE 1: U'[x][19456] = d1 x Wb.  MODE 2: s_flat = h1 x U'.
// ---------------------------------------------------------------------------
template <int MODE>
__global__ __launch_bounds__(256)
void gemm_mfma(const unsigned short* __restrict__ Ah, const unsigned short* __restrict__ Al,
               const unsigned short* __restrict__ Bh, const unsigned short* __restrict__ Bl,
               float* __restrict__ outF, unsigned short* __restrict__ outUh,
               unsigned short* __restrict__ outUl, const unsigned short* __restrict__ zbuf,
               int c0) {
    __shared__ short Als[128 * 64];
    __shared__ short Bls[128 * 64];

    const int t = threadIdx.x;
    const int lane = t & 63;
    const int w = t >> 6, wr = w >> 1, wc = w & 1;
    const int bx = blockIdx.x, n0 = blockIdx.y * 128;

    int arow0;
    if constexpr (MODE == 1) {
        arow0 = c0 * 256 + bx * 128;
    } else {
        arow0 = (c0 + blockIdx.z) * 256 + bx * 128;
    }

    int kcd[4];
    size_t rowA[4], rowB[4];
    const short* ldsA[4];
    const short* ldsB[4];
    #pragma unroll
    for (int c4 = 0; c4 < 4; ++c4) {
        int ch = c4 * 256 + t;
        int r = ch >> 3;
        kcd[c4] = (ch & 7) ^ (r & 7);
        rowA[c4] = (size_t)(arow0 + r) * 304;
        if constexpr (MODE == 1) {
            rowB[c4] = (size_t)(n0 + r) * 304;
        } else {
            int rb = n0 + r;
            rowB[c4] = (size_t)(blockIdx.z * 256 + (rb >> 6)) * 19456 +
                       (size_t)(rb & 63) * 304;
        }
        int wavebase = (c4 * 256 + (t & ~63)) * 8;
        ldsA[c4] = &Als[wavebase];
        ldsB[c4] = &Bls[wavebase];
    }

    f32x4 acc[4][4];
    #pragma unroll
    for (int i = 0; i < 4; ++i)
        #pragma unroll
        for (int j = 0; j < 4; ++j)
            acc[i][j] = (f32x4){0.f, 0.f, 0.f, 0.f};

    const int rowA_l = wr * 64 + (lane & 15);
    const int rowB_l = wc * 64 + (lane & 15);
    const int csub = lane >> 4;
    const int cxor = lane & 7;

    for (int it = 0; it < 15; ++it) {
        const int it8 = it * 8;
        #pragma unroll
        for (int c4 = 0; c4 < 4; ++c4) {
            int kg = it8 + kcd[c4];
            {
                const unsigned short* sa;
                if (kg < 38)       sa = Ah + rowA[c4] + (size_t)kg * 8;
                else if (kg < 76)  sa = Al + rowA[c4] + (size_t)(kg - 38) * 8;
                else if (kg < 114) sa = Ah + rowA[c4] + (size_t)(kg - 76) * 8;
                else               sa = zbuf;
                gload16(sa, ldsA[c4]);
            }
            {
                const unsigned short* sb;
                if (kg < 38)       sb = Bh + rowB[c4] + (size_t)kg * 8;
                else if (kg < 76)  sb = Bh + rowB[c4] + (size_t)(kg - 38) * 8;
                else if (kg < 114) sb = Bl + rowB[c4] + (size_t)(kg - 76) * 8;
                else               sb = zbuf;
                gload16(sb, ldsB[c4]);
            }
        }
        __syncthreads();

        #pragma unroll
        for (int kh = 0; kh < 2; ++kh) {
            const int kcr = ((kh * 4 + csub) ^ cxor) * 8;
            bf16x8 af[4], bfr[4];
            #pragma unroll
            for (int f = 0; f < 4; ++f)
                af[f] = *(const bf16x8*)&Als[(rowA_l + f * 16) * 64 + kcr];
            #pragma unroll
            for (int f = 0; f < 4; ++f)
                bfr[f] = *(const bf16x8*)&Bls[(rowB_l + f * 16) * 64 + kcr];
            #pragma unroll
            for (int fr = 0; fr < 4; ++fr)
                #pragma unroll
                for (int fb = 0; fb < 4; ++fb)
                    acc[fr][fb] = __builtin_amdgcn_mfma_f32_16x16x32_bf16(
                        af[fr], bfr[fb], acc[fr][fb], 0, 0, 0);
        }
        __syncthreads();
    }

    const int mbase = bx * 128 + wr * 64 + ((lane >> 4) << 2);
    const int nbase = n0 + wc * 64 + (lane & 15);
    #pragma unroll
    for (int fb = 0; fb < 4; ++fb) {
        const int n = nbase + fb * 16;
        if constexpr (MODE == 1) {
            #pragma unroll
            for (int fr = 0; fr < 4; ++fr) {
                #pragma unroll
                for (int reg = 0; reg < 4; ++reg) {
                    int xloc = mbase + fr * 16 + reg;
                    float v = acc[fr][fb][reg];
                    unsigned short hi = f2bf(v);
                    unsigned short lo = f2bf(v - bf2f(hi));
                    size_t o = (size_t)xloc * 19456 + n;
                    outUh[o] = hi;
                    outUl[o] = lo;
                }
            }
        } else {
            const int xx = n >> 6, lt = n & 63;
            const size_t sbase = (size_t)(c0 + blockIdx.z) * 4194304 +
                                 (size_t)xx * 16384 + lt;
            #pragma unroll
            for (int fr = 0; fr < 4; ++fr) {
                #pragma unroll
                for (int reg = 0; reg < 4; ++reg) {
                    int y = mbase + fr * 16 + reg;
                    outF[sbase + (size_t)y * 64] = acc[fr][fb][reg];
                }
            }
        }
    }
}

// ---------------------------------------------------------------------------
// Forward CRF (num - den); softmax cancels. Masked rows skipped.
// ---------------------------------------------------------------------------
__global__ __launch_bounds__(256, 4)
void fwd_kernel(const float* __restrict__ s_flat, const int* __restrict__ lenB,
                const int* __restrict__ maskI, const int* __restrict__ labels,
                const float* __restrict__ trans, const float* __restrict__ start_trans,
                const float* __restrict__ end_trans, float* __restrict__ rowterm) {
    __shared__ float T[4096];
    const int t = threadIdx.x;
    for (int i = t; i < 4096; i += 256) T[i] = trans[i];
    __syncthreads();

    const int lane = t & 63, wid = t >> 6;
    const int row = blockIdx.x * 4 + wid;
    if (maskI[row] == 0) {
        if (lane == 0) rowterm[row] = 0.f;
        return;
    }
    const int len = lenB[row >> 8];
    const float* srow = s_flat + (size_t)row * 16384;
    const int* lrow = labels + (size_t)row * 256;

    float Ec[64];
    #pragma unroll
    for (int p = 0; p < 64; ++p) Ec[p] = __expf(T[p * 64 + lane]);

    const float et = end_trans[lane];

    float sv = srow[lane];
    int tagprev = lrow[0];
    float num = start_trans[tagprev] + rlf(sv, tagprev);
    float alpha = start_trans[lane] + sv;
    float sv_pre = srow[64 + lane];

    for (int y = 1; y < len; ++y) {
        sv = sv_pre;
        int ynext = (y + 1 < len) ? (y + 1) : (len - 1);
        sv_pre = srow[ynext * 64 + lane];

        const int tag = lrow[y];
        num += rlf(sv, tag) + T[tagprev * 64 + tag];
        tagprev = tag;

        float am = alpha;
        #pragma unroll
        for (int m = 32; m; m >>= 1) am = fmaxf(am, __shfl_xor(am, m));
        float ea = __expf(alpha - am);
        float a0 = 0.f, a1 = 0.f, a2 = 0.f, a3 = 0.f;
        #pragma unroll
        for (int p = 0; p < 64; p += 4) {
            a0 = fmaf(rlf(ea, p + 0), Ec[p + 0], a0);
            a1 = fmaf(rlf(ea, p + 1), Ec[p + 1], a1);
            a2 = fmaf(rlf(ea, p + 2), Ec[p + 2], a2);
            a3 = fmaf(rlf(ea, p + 3), Ec[p + 3], a3);
        }
        alpha = am + __logf((a0 + a1) + (a2 + a3)) + sv;
    }

    num += end_trans[tagprev];
    float da = alpha + et;
    float dmx = da;
    #pragma unroll
    for (int m = 32; m; m >>= 1) dmx = fmaxf(dmx, __shfl_xor(dmx, m));
    float ds = __expf(da - dmx);
    #pragma unroll
    for (int m = 32; m; m >>= 1) ds += __shfl_xor(ds, m);
    float den = dmx + __logf(ds);
    if (lane == 0) rowterm[row] = num - den;
}

// ---------------------------------------------------------------------------
// Viterbi forward, max-only. Stores vs state per step.
// ---------------------------------------------------------------------------
__global__ __launch_bounds__(256, 4)
void vitf_kernel(const float* __restrict__ s_flat, const int* __restrict__ lenB,
                 const float* __restrict__ trans, const float* __restrict__ start_trans,
                 const float* __restrict__ end_trans, float* __restrict__ vsb,
                 float* __restrict__ decoded) {
    const int t = threadIdx.x;
    const int lane = t & 63, wid = t >> 6;
    const int row = blockIdx.x * 4 + wid;
    const int len = lenB[row >> 8];
    const float* srow = s_flat + (size_t)row * 16384;
    float* vrow = vsb + (size_t)row * 16384;

    float sv = srow[lane];
    float vs = start_trans[lane] + sv;
    float sv_pre = srow[64 + lane];

    for (int y = 1; y < len; ++y) {
        vrow[(y - 1) * 64 + lane] = vs;
        float svc = sv_pre;
        int ynext = (y + 1 < len) ? (y + 1) : (len - 1);
        sv_pre = srow[ynext * 64 + lane];

        float m0 = -3.4e38f, m1 = -3.4e38f, m2 = -3.4e38f, m3 = -3.4e38f;
        #pragma unroll
        for (int p = 0; p < 64; p += 8) {
            float t0 = rlf(vs, p + 0) + trans[(p + 0) * 64 + lane];
            float t1 = rlf(vs, p + 1) + trans[(p + 1) * 64 + lane];
            m0 = fmaxf(fmaxf(t0, t1), m0);
            float t2 = rlf(vs, p + 2) + trans[(p + 2) * 64 + lane];
            float t3 = rlf(vs, p + 3) + trans[(p + 3) * 64 + lane];
            m1 = fmaxf(fmaxf(t2, t3), m1);
            float t4 = rlf(vs, p + 4) + trans[(p + 4) * 64 + lane];
            float t5 = rlf(vs, p + 5) + trans[(p + 5) * 64 + lane];
            m2 = fmaxf(fmaxf(t4, t5), m2);
            float t6 = rlf(vs, p + 6) + trans[(p + 6) * 64 + lane];
            float t7 = rlf(vs, p + 7) + trans[(p + 7) * 64 + lane];
            m3 = fmaxf(fmaxf(t6, t7), m3);
        }
        vs = fmaxf(fmaxf(m0, m1), fmaxf(m2, m3)) + svc;
    }

    float fe = vs + end_trans[lane];
    float mx = fe;
    #pragma unroll
    for (int m = 32; m; m >>= 1) mx = fmaxf(mx, __shfl_xor(mx, m));
    unsigned long long msk = __ballot(fe == mx);
    int fi = (int)__builtin_ctzll(msk);

    if (lane == 0) decoded[(size_t)row * 256 + 255] = (float)fi;
}

// ---------------------------------------------------------------------------
// Viterbi backward: recompute argmax per step from stored vs state.
// ---------------------------------------------------------------------------
__global__ __launch_bounds__(256)
void vitb_kernel(const float* __restrict__ vsb, const int* __restrict__ lenB,
                 const float* __restrict__ trans, float* __restrict__ decoded) {
    __shared__ float Tt[64][65];
    const int t = threadIdx.x;
    for (int i = t; i < 4096; i += 256) {
        int p = i >> 6, c = i & 63;
        Tt[c][p] = trans[i];
    }
    __syncthreads();

    const int lane = t & 63, wid = t >> 6;
    const int row = blockIdx.x * 4 + wid;
    const int len = lenB[row >> 8];
    const float* vrow = vsb + (size_t)row * 16384;
    float* drow = decoded + (size_t)row * 256;

    int cur = (int)drow[255];

    for (int y = len - 1 + lane; y < 255; y += 64) drow[y] = (float)cur;

    float v0 = vrow[(len - 2) * 64 + lane];
    float v1 = (len >= 3) ? vrow[(len - 3) * 64 + lane] : 0.f;

    for (int y = len - 2; y >= 0; --y) {
        float vy = v0;
        v0 = v1;
        v1 = (y >= 2) ? vrow[(y - 2) * 64 + lane] : 0.f;

        float tp = vy + Tt[cur][lane];
        float mx = tp;
        #pragma unroll
        for (int m = 32; m; m >>= 1) mx = fmaxf(mx, __shfl_xor(mx, m));
        unsigned long long msk = __ballot(tp == mx);
        cur = (int)__builtin_ctzll(msk);
        if (lane == 0) drow[y] = (float)cur;
    }
}

// ---------------------------------------------------------------------------
// FALLBACK path (small workspace): hist-based Viterbi + backtrack.
// ---------------------------------------------------------------------------
__global__ __launch_bounds__(256, 3)
void vit_kernel(const float* __restrict__ s_flat, const int* __restrict__ lenB,
                const float* __restrict__ trans, const float* __restrict__ start_trans,
                const float* __restrict__ end_trans, unsigned char* __restrict__ hist,
                float* __restrict__ decoded) {
    const int t = threadIdx.x;
    const int lane = t & 63, wid = t >> 6;
    const int row = blockIdx.x * 4 + wid;
    const int len = lenB[row >> 8];
    const float* srow = s_flat + (size_t)row * 16384;
    unsigned char* hrow = hist + (size_t)row * 16320;

    float sv = srow[lane];
    float vs = start_trans[lane] + sv;
    float sv_pre = srow[64 + lane];

    for (int y = 1; y < len; ++y) {
        sv = sv_pre;
        int ynext = (y + 1 < len) ? (y + 1) : (len - 1);
        sv_pre = srow[ynext * 64 + lane];

        float b0 = -3.4e38f, b1 = -3.4e38f, b2 = -3.4e38f, b3 = -3.4e38f;
        int i0 = 0, i1 = 1, i2 = 2, i3 = 3;
        #pragma unroll
        for (int p = 0; p < 64; p += 4) {
            float t0 = rlf(vs, p + 0) + trans[(p + 0) * 64 + lane]; if (t0 > b0) { b0 = t0; i0 = p + 0; }
            float t1 = rlf(vs, p + 1) + trans[(p + 1) * 64 + lane]; if (t1 > b1) { b1 = t1; i1 = p + 1; }
            float t2 = rlf(vs, p + 2) + trans[(p + 2) * 64 + lane]; if (t2 > b2) { b2 = t2; i2 = p + 2; }
            float t3 = rlf(vs, p + 3) + trans[(p + 3) * 64 + lane]; if (t3 > b3) { b3 = t3; i3 = p + 3; }
        }
        bool c;
        c = (b1 > b0) || (b1 == b0 && i1 < i0);
        float bA = c ? b1 : b0; int iA = c ? i1 : i0;
        c = (b3 > b2) || (b3 == b2 && i3 < i2);
        float bB = c ? b3 : b2; int iB = c ? i3 : i2;
        c = (bB > bA) || (bB == bA && iB < iA);
        float bbv = c ? bB : bA; int bi = c ? iB : iA;

        hrow[(size_t)(y - 1) * 64 + lane] = (unsigned char)bi;
        vs = bbv + sv;
    }

    float fv = vs + end_trans[lane]; int fi = lane;
    #pragma unroll
    for (int m = 32; m; m >>= 1) {
        float ov = __shfl_xor(fv, m);
        int oi = __shfl_xor(fi, m);
        bool cc = (ov > fv) || (ov == fv && oi < fi);
        fv = cc ? ov : fv; fi = cc ? oi : fi;
    }

    if (lane == 0) decoded[(size_t)row * 256 + 255] = (float)fi;
}

__global__ __launch_bounds__(256)
void backtrack_kernel(const unsigned char* __restrict__ hist, const int* __restrict__ lenB,
                      float* __restrict__ decoded) {
    const int lane = threadIdx.x & 63, wid = threadIdx.x >> 6;
    const int row = blockIdx.x * 4 + wid;
    const int len = lenB[row >> 8];
    const unsigned char* hrow = hist + (size_t)row * 16320;
    float* drow = decoded + (size_t)row * 256;

    int cur = (int)drow[255];
    for (int y = len - 1 + lane; y < 255; y += 64) drow[y] = (float)cur;

    int t0 = len - 2;
    int c0 = (int)hrow[(t0 - 0) * 64 + lane];
    int c1 = (int)hrow[(t0 - 1) * 64 + lane];
    int c2 = (int)hrow[(t0 - 2) * 64 + lane];
    int c3 = (int)hrow[(t0 - 3) * 64 + lane];

    for (int y = t0; y >= 0; y -= 4) {
        int yn = y - 4;
        int n0 = 0, n1 = 0, n2 = 0, n3 = 0;
        if (yn - 0 >= 0) n0 = (int)hrow[(yn - 0) * 64 + lane];
        if (yn - 1 >= 0) n1 = (int)hrow[(yn - 1) * 64 + lane];
        if (yn - 2 >= 0) n2 = (int)hrow[(yn - 2) * 64 + lane];
        if (yn - 3 >= 0) n3 = (int)hrow[(yn - 3) * 64 + lane];

        cur = rli(c0, cur);
        if (lane == 0) drow[y] = (float)cur;
        if (y - 1 >= 0) { cur = rli(c1, cur); if (lane == 0) drow[y - 1] = (float)cur; }
        if (y - 2 >= 0) { cur = rli(c2, cur); if (lane == 0) drow[y - 2] = (float)cur; }
        if (y - 3 >= 0) { cur = rli(c3, cur); if (lane == 0) drow[y - 3] = (float)cur; }

        c0 = n0; c1 = n1; c2 = n2; c3 = n3;
    }
}

__global__ void loss_kernel(const float* __restrict__ rowterm, float* __restrict__ out) {
    __shared__ float wsum[4];
    int t = threadIdx.x;
    float s = 0.f;
    for (int i = t; i < 4096; i += 256) s += rowterm[i];
    #pragma unroll
    for (int m = 32; m; m >>= 1) s += __shfl_xor(s, m);
    if ((t & 63) == 0) wsum[t >> 6] = s;
    __syncthreads();
    if (t == 0) out[0] = -(wsum[0] + wsum[1] + wsum[2] + wsum[3]);
}

extern "C" void kernel_launch(void* const* d_in, const int* in_sizes, int n_in,
                              void* d_out, int out_size, void* d_ws, size_t ws_size,
                              hipStream_t stream) {
    const float* input  = (const float*)d_in[0];
    const void*  mraw   = d_in[1];
    const int*   labels = (const int*)d_in[2];
    const float* Wh_in  = (const float*)d_in[3];
    const float* bh     = (const float*)d_in[4];
    const float* Wd_in  = (const float*)d_in[5];
    const float* bd     = (const float*)d_in[6];
    const float* Wbil   = (const float*)d_in[7];
    const float* stt    = (const float*)d_in[8];
    const float* trans  = (const float*)d_in[9];
    const float* ett    = (const float*)d_in[10];

    float* out     = (float*)d_out;
    float* s_flat  = out + 1;
    float* decoded = out + 1 + (size_t)67108864;

    char* ws = (char*)d_ws;
    size_t off = 0;
    unsigned short* h1h = (unsigned short*)(ws + off); off += (size_t)4096 * 304 * 2;
    unsigned short* h1l = (unsigned short*)(ws + off); off += (size_t)4096 * 304 * 2;
    unsigned short* d1h = (unsigned short*)(ws + off); off += (size_t)4096 * 304 * 2;
    unsigned short* d1l = (unsigned short*)(ws + off); off += (size_t)4096 * 304 * 2;
    unsigned short* Wbh = (unsigned short*)(ws + off); off += (size_t)19456 * 304 * 2;
    unsigned short* Wbl = (unsigned short*)(ws + off); off += (size_t)19456 * 304 * 2;
    int* maskI = (int*)(ws + off); off += 16384;
    int* lenB  = (int*)(ws + off); off += 256;
    int* zbuf  = (int*)(ws + off); off += 256;
    float* rowterm = (float*)(ws + off); off += 16384;

    const size_t vsb_bytes = (size_t)4096 * 16384 * 4;
    const size_t hist_bytes = (size_t)4096 * 16320;
    const size_t perb = (size_t)256 * 19456 * 2 * 2;

    bool newpath = (ws_size >= off + vsb_bytes + perb);
    float* vsb = nullptr;
    unsigned char* hist = nullptr;
    if (newpath) { vsb  = (float*)(ws + off); off += vsb_bytes; }
    else         { hist = (unsigned char*)(ws + off); off += hist_bytes; }

    unsigned short* Uh = (unsigned short*)(ws + off);
    size_t avail = (ws_size > off) ? ws_size - off : 0;
    int CB = (int)(avail / perb);
    if (CB < 1) CB = 1;
    if (CB > 16) CB = 16;
    unsigned short* Ul = Uh + (size_t)CB * 256 * 19456;

    mask_cvt_kernel<<<16, 256, 0, stream>>>(mraw, maskI, lenB, zbuf);
    wsplit_kernel<<<dim3(64, 19), 256, 0, stream>>>(Wbil, Wbh, Wbl);
    mlp_kernel<<<dim3(32, 3, 2), 256, 0, stream>>>(input, Wh_in, bh, Wd_in, bd,
                                                   h1h, h1l, d1h, d1l);

    for (int c0 = 0; c0 < 16; c0 += CB) {
        int cb = (CB < 16 - c0) ? CB : (16 - c0);
        gemm_mfma<1><<<dim3(cb * 2, 152), 256, 0, stream>>>(
            d1h, d1l, Wbh, Wbl, nullptr, Uh, Ul, (const unsigned short*)zbuf, c0);
        gemm_mfma<2><<<dim3(2, 128, cb), 256, 0, stream>>>(
            h1h, h1l, Uh, Ul, s_flat, nullptr, nullptr, (const unsigned short*)zbuf, c0);
    }

    fwd_kernel<<<1024, 256, 0, stream>>>(s_flat, lenB, maskI, labels, trans, stt, ett,
                                         rowterm);
    if (newpath) {
        vitf_kernel<<<1024, 256, 0, stream>>>(s_flat, lenB, trans, stt, ett, vsb, decoded);
        vitb_kernel<<<1024, 256, 0, stream>>>(vsb, lenB, trans, decoded);
    } else {
        vit_kernel<<<1024, 256, 0, stream>>>(s_flat, lenB, trans, stt, ett, hist, decoded);
        backtrack_kernel<<<1024, 256, 0, stream>>>(hist, lenB, decoded);
    }
    loss_kernel<<<1, 256, 0, stream>>>(rowterm, out);
}

// Round 14
// 1297.586 us; speedup vs baseline: 1.0724x; 1.0242x over previous
//
#include <hip/hip_runtime.h>
#include <math.h>

// B=16, N=256, H=1024, HID=300, HID1=301 (pad 304), L=64, M=B*N=4096
// Config: R9 core (1334 us) + grid-fused fwd||vitf (disjoint-branch kernel).
// Falsified levers (do not retry): same-loop fwd+vitf fusion (R10, spilled
// Ec[64] to scratch), CB<=4 L3-cap (R11), double-buffered gemm LDS (R12).

typedef short bf16x8 __attribute__((ext_vector_type(8)));
typedef float f32x4 __attribute__((ext_vector_type(4)));

__device__ __forceinline__ float rlf(float v, int l) {
    return __uint_as_float(__builtin_amdgcn_readlane(__float_as_uint(v), (unsigned)l));
}
__device__ __forceinline__ int rli(int v, int l) {
    return __builtin_amdgcn_readlane(v, (unsigned)l);
}
__device__ __forceinline__ unsigned short f2bf(float x) {
    union { float f; unsigned u; } c; c.f = x;
    unsigned r = c.u + 0x7FFF + ((c.u >> 16) & 1);
    return (unsigned short)(r >> 16);
}
__device__ __forceinline__ float bf2f(unsigned short h) {
    union { unsigned u; float f; } c; c.u = ((unsigned)h) << 16; return c.f;
}
__device__ __forceinline__ void gload16(const void* g, const void* lds) {
    __builtin_amdgcn_global_load_lds(
        (const __attribute__((address_space(1))) void*)g,
        (__attribute__((address_space(3))) void*)lds, 16, 0, 0);
}

// ---------------------------------------------------------------------------
__global__ void mask_cvt_kernel(const void* __restrict__ mraw, int* __restrict__ maskI,
                                int* __restrict__ lenB, int* __restrict__ zbuf) {
    int b = blockIdx.x, t = threadIdx.x;
    if (b == 0 && t < 8) zbuf[t] = 0;
    int i = b * 256 + t;
    unsigned int w0 = ((const unsigned int*)mraw)[0];
    int v;
    if (w0 == 1u)               v = ((const int*)mraw)[i];
    else if (w0 == 0x3F800000u) v = (((const float*)mraw)[i] != 0.f) ? 1 : 0;
    else                        v = ((const unsigned char*)mraw)[i] ? 1 : 0;
    maskI[i] = v;
    __shared__ int sh[4];
    int s = v;
    #pragma unroll
    for (int m = 32; m; m >>= 1) s += __shfl_xor(s, m);
    if ((t & 63) == 0) sh[t >> 6] = s;
    __syncthreads();
    if (t == 0) lenB[b] = sh[0] + sh[1] + sh[2] + sh[3];
}

// ---------------------------------------------------------------------------
__global__ __launch_bounds__(256)
void wsplit_kernel(const float* __restrict__ Wbil,
                   unsigned short* __restrict__ Wbh, unsigned short* __restrict__ Wbl) {
    __shared__ float Tile[304][17];
    const int l = blockIdx.x, jt = blockIdx.y, t = threadIdx.x;
    const int j0 = jt * 16;
    {
        int jj = t & 15, it = t >> 4;
        #pragma unroll
        for (int ib = 0; ib < 19; ++ib) {
            int i = ib * 16 + it;
            float v = 0.f;
            if (i < 301 && j0 + jj < 301)
                v = Wbil[(size_t)l * 90601 + (size_t)i * 301 + j0 + jj];
            Tile[i][jj] = v;
        }
    }
    __syncthreads();
    {
        int il = t & 15, jj = t >> 4;
        #pragma unroll
        for (int ib = 0; ib < 19; ++ib) {
            int i = ib * 16 + il;
            float v = Tile[i][jj];
            unsigned short hi = f2bf(v);
            unsigned short lo = f2bf(v - bf2f(hi));
            size_t o = ((size_t)(l * 304 + j0 + jj)) * 304 + i;
            Wbh[o] = hi; Wbl[o] = lo;
        }
    }
}

// ---------------------------------------------------------------------------
__global__ __launch_bounds__(256)
void mlp_kernel(const float* __restrict__ A,
                const float* __restrict__ Wh, const float* __restrict__ bh_,
                const float* __restrict__ Wd, const float* __restrict__ bd_,
                unsigned short* __restrict__ h1h, unsigned short* __restrict__ h1l,
                unsigned short* __restrict__ d1h, unsigned short* __restrict__ d1l) {
    constexpr int BM = 128, BN = 128, BK = 16;
    __shared__ float As[BK][BM + 4];
    __shared__ float Bs[BK][BN + 4];

    const int t = threadIdx.x;
    const int tn = t & 15, tm = t >> 4;
    const size_t a_row0 = (size_t)blockIdx.x * BM;
    const int n0 = blockIdx.y * BN;
    const int z = blockIdx.z;
    const float* Bm = z ? Wd : Wh;
    const float* bias = z ? bd_ : bh_;
    unsigned short* Ch = z ? d1h : h1h;
    unsigned short* Cl = z ? d1l : h1l;

    float acc[2][2][4][4] = {};
    const int ar = t >> 2, ak = (t & 3) * 4;

    for (int k0 = 0; k0 < 1024; k0 += BK) {
        {
            const float* ap = A + (a_row0 + ar) * 1024 + k0 + ak;
            float4 v0 = *(const float4*)ap;
            float4 v1 = *(const float4*)(ap + 64 * 1024);
            As[ak + 0][ar] = v0.x; As[ak + 1][ar] = v0.y;
            As[ak + 2][ar] = v0.z; As[ak + 3][ar] = v0.w;
            As[ak + 0][64 + ar] = v1.x; As[ak + 1][64 + ar] = v1.y;
            As[ak + 2][64 + ar] = v1.z; As[ak + 3][64 + ar] = v1.w;
        }
        {
            int r1 = min(n0 + ar, 299), r2 = min(n0 + 64 + ar, 299);
            const float* q1 = Bm + (size_t)r1 * 1024 + k0 + ak;
            const float* q2 = Bm + (size_t)r2 * 1024 + k0 + ak;
            float4 v0 = *(const float4*)q1;
            float4 v1 = *(const float4*)q2;
            Bs[ak + 0][ar] = v0.x; Bs[ak + 1][ar] = v0.y;
            Bs[ak + 2][ar] = v0.z; Bs[ak + 3][ar] = v0.w;
            Bs[ak + 0][64 + ar] = v1.x; Bs[ak + 1][64 + ar] = v1.y;
            Bs[ak + 2][64 + ar] = v1.z; Bs[ak + 3][64 + ar] = v1.w;
        }
        __syncthreads();
        #pragma unroll
        for (int kk = 0; kk < BK; ++kk) {
            float4 a0 = *(const float4*)&As[kk][tm * 4];
            float4 a1 = *(const float4*)&As[kk][64 + tm * 4];
            float4 b0 = *(const float4*)&Bs[kk][tn * 4];
            float4 b1 = *(const float4*)&Bs[kk][64 + tn * 4];
            float av[2][4] = {{a0.x, a0.y, a0.z, a0.w}, {a1.x, a1.y, a1.z, a1.w}};
            float bv[2][4] = {{b0.x, b0.y, b0.z, b0.w}, {b1.x, b1.y, b1.z, b1.w}};
            #pragma unroll
            for (int ih = 0; ih < 2; ++ih)
                #pragma unroll
                for (int ii = 0; ii < 4; ++ii)
                    #pragma unroll
                    for (int jh = 0; jh < 2; ++jh)
                        #pragma unroll
                        for (int jj = 0; jj < 4; ++jj)
                            acc[ih][jh][ii][jj] =
                                fmaf(av[ih][ii], bv[jh][jj], acc[ih][jh][ii][jj]);
        }
        __syncthreads();
    }

    #pragma unroll
    for (int ih = 0; ih < 2; ++ih) {
        #pragma unroll
        for (int ii = 0; ii < 4; ++ii) {
            int r = ih * 64 + tm * 4 + ii;
            #pragma unroll
            for (int jh = 0; jh < 2; ++jh) {
                int n = n0 + jh * 64 + tn * 4;
                if (n < 304) {
                    float o[4];
                    #pragma unroll
                    for (int q = 0; q < 4; ++q) {
                        int nq = n + q;
                        float v = acc[ih][jh][ii][q];
                        o[q] = (nq < 300) ? fmaxf(v + bias[min(nq, 299)], 0.f)
                                          : ((nq == 300) ? 1.f : 0.f);
                    }
                    ushort4 h4, l4;
                    h4.x = f2bf(o[0]); l4.x = f2bf(o[0] - bf2f(h4.x));
                    h4.y = f2bf(o[1]); l4.y = f2bf(o[1] - bf2f(h4.y));
                    h4.z = f2bf(o[2]); l4.z = f2bf(o[2] - bf2f(h4.z));
                    h4.w = f2bf(o[3]); l4.w = f2bf(o[3] - bf2f(h4.w));
                    size_t base = (a_row0 + r) * 304 + n;
                    *(ushort4*)&Ch[base] = h4;
                    *(ushort4*)&Cl[base] = l4;
                }
            }
        }
    }
}

// ---------------------------------------------------------------------------
// Split-bf16 MFMA GEMM, 3-term (K'=912 padded to 960, 15 iters of 64 k').
// MODE 1: U'[x][19456] = d1 x Wb.  MODE 2: s_flat = h1 x U'.
// ---------------------------------------------------------------------------
template <int MODE>
__global__ __launch_bounds__(256)
void gemm_mfma(const unsigned short* __restrict__ Ah, const unsigned short* __restrict__ Al,
               const unsigned short* __restrict__ Bh, const unsigned short* __restrict__ Bl,
               float* __restrict__ outF, unsigned short* __restrict__ outUh,
               unsigned short* __restrict__ outUl, const unsigned short* __restrict__ zbuf,
               int c0) {
    __shared__ short Als[128 * 64];
    __shared__ short Bls[128 * 64];

    const int t = threadIdx.x;
    const int lane = t & 63;
    const int w = t >> 6, wr = w >> 1, wc = w & 1;
    const int bx = blockIdx.x, n0 = blockIdx.y * 128;

    int arow0;
    if constexpr (MODE == 1) {
        arow0 = c0 * 256 + bx * 128;
    } else {
        arow0 = (c0 + blockIdx.z) * 256 + bx * 128;
    }

    int kcd[4];
    size_t rowA[4], rowB[4];
    const short* ldsA[4];
    const short* ldsB[4];
    #pragma unroll
    for (int c4 = 0; c4 < 4; ++c4) {
        int ch = c4 * 256 + t;
        int r = ch >> 3;
        kcd[c4] = (ch & 7) ^ (r & 7);
        rowA[c4] = (size_t)(arow0 + r) * 304;
        if constexpr (MODE == 1) {
            rowB[c4] = (size_t)(n0 + r) * 304;
        } else {
            int rb = n0 + r;
            rowB[c4] = (size_t)(blockIdx.z * 256 + (rb >> 6)) * 19456 +
                       (size_t)(rb & 63) * 304;
        }
        int wavebase = (c4 * 256 + (t & ~63)) * 8;
        ldsA[c4] = &Als[wavebase];
        ldsB[c4] = &Bls[wavebase];
    }

    f32x4 acc[4][4];
    #pragma unroll
    for (int i = 0; i < 4; ++i)
        #pragma unroll
        for (int j = 0; j < 4; ++j)
            acc[i][j] = (f32x4){0.f, 0.f, 0.f, 0.f};

    const int rowA_l = wr * 64 + (lane & 15);
    const int rowB_l = wc * 64 + (lane & 15);
    const int csub = lane >> 4;
    const int cxor = lane & 7;

    for (int it = 0; it < 15; ++it) {
        const int it8 = it * 8;
        #pragma unroll
        for (int c4 = 0; c4 < 4; ++c4) {
            int kg = it8 + kcd[c4];
            {
                const unsigned short* sa;
                if (kg < 38)       sa = Ah + rowA[c4] + (size_t)kg * 8;
                else if (kg < 76)  sa = Al + rowA[c4] + (size_t)(kg - 38) * 8;
                else if (kg < 114) sa = Ah + rowA[c4] + (size_t)(kg - 76) * 8;
                else               sa = zbuf;
                gload16(sa, ldsA[c4]);
            }
            {
                const unsigned short* sb;
                if (kg < 38)       sb = Bh + rowB[c4] + (size_t)kg * 8;
                else if (kg < 76)  sb = Bh + rowB[c4] + (size_t)(kg - 38) * 8;
                else if (kg < 114) sb = Bl + rowB[c4] + (size_t)(kg - 76) * 8;
                else               sb = zbuf;
                gload16(sb, ldsB[c4]);
            }
        }
        __syncthreads();

        #pragma unroll
        for (int kh = 0; kh < 2; ++kh) {
            const int kcr = ((kh * 4 + csub) ^ cxor) * 8;
            bf16x8 af[4], bfr[4];
            #pragma unroll
            for (int f = 0; f < 4; ++f)
                af[f] = *(const bf16x8*)&Als[(rowA_l + f * 16) * 64 + kcr];
            #pragma unroll
            for (int f = 0; f < 4; ++f)
                bfr[f] = *(const bf16x8*)&Bls[(rowB_l + f * 16) * 64 + kcr];
            #pragma unroll
            for (int fr = 0; fr < 4; ++fr)
                #pragma unroll
                for (int fb = 0; fb < 4; ++fb)
                    acc[fr][fb] = __builtin_amdgcn_mfma_f32_16x16x32_bf16(
                        af[fr], bfr[fb], acc[fr][fb], 0, 0, 0);
        }
        __syncthreads();
    }

    const int mbase = bx * 128 + wr * 64 + ((lane >> 4) << 2);
    const int nbase = n0 + wc * 64 + (lane & 15);
    #pragma unroll
    for (int fb = 0; fb < 4; ++fb) {
        const int n = nbase + fb * 16;
        if constexpr (MODE == 1) {
            #pragma unroll
            for (int fr = 0; fr < 4; ++fr) {
                #pragma unroll
                for (int reg = 0; reg < 4; ++reg) {
                    int xloc = mbase + fr * 16 + reg;
                    float v = acc[fr][fb][reg];
                    unsigned short hi = f2bf(v);
                    unsigned short lo = f2bf(v - bf2f(hi));
                    size_t o = (size_t)xloc * 19456 + n;
                    outUh[o] = hi;
                    outUl[o] = lo;
                }
            }
        } else {
            const int xx = n >> 6, lt = n & 63;
            const size_t sbase = (size_t)(c0 + blockIdx.z) * 4194304 +
                                 (size_t)xx * 16384 + lt;
            #pragma unroll
            for (int fr = 0; fr < 4; ++fr) {
                #pragma unroll
                for (int reg = 0; reg < 4; ++reg) {
                    int y = mbase + fr * 16 + reg;
                    outF[sbase + (size_t)y * 64] = acc[fr][fb][reg];
                }
            }
        }
    }
}

// ---------------------------------------------------------------------------
// Grid-fused CRF: blockIdx.y == 0 -> forward (num-den); == 1 -> Viterbi
// max-only forward. Disjoint branches (no simultaneous register liveness).
// ---------------------------------------------------------------------------
__global__ __launch_bounds__(256, 4)
void crfpar_kernel(const float* __restrict__ s_flat, const int* __restrict__ lenB,
                   const int* __restrict__ maskI, const int* __restrict__ labels,
                   const float* __restrict__ trans, const float* __restrict__ start_trans,
                   const float* __restrict__ end_trans, float* __restrict__ rowterm,
                   float* __restrict__ vsb, float* __restrict__ decoded) {
    const int t = threadIdx.x;
    const int lane = t & 63, wid = t >> 6;
    const int row = blockIdx.x * 4 + wid;
    const int len = lenB[row >> 8];

    if (blockIdx.y == 0) {
        // ================= forward (num - den) =================
        __shared__ float T[4096];
        for (int i = t; i < 4096; i += 256) T[i] = trans[i];
        __syncthreads();

        if (maskI[row] == 0) {
            if (lane == 0) rowterm[row] = 0.f;
            return;
        }
        const float* srow = s_flat + (size_t)row * 16384;
        const int* lrow = labels + (size_t)row * 256;

        float Ec[64];
        #pragma unroll
        for (int p = 0; p < 64; ++p) Ec[p] = __expf(T[p * 64 + lane]);

        const float et = end_trans[lane];

        float sv = srow[lane];
        int tagprev = lrow[0];
        float num = start_trans[tagprev] + rlf(sv, tagprev);
        float alpha = start_trans[lane] + sv;
        float sv_pre = srow[64 + lane];

        for (int y = 1; y < len; ++y) {
            sv = sv_pre;
            int ynext = (y + 1 < len) ? (y + 1) : (len - 1);
            sv_pre = srow[ynext * 64 + lane];

            const int tag = lrow[y];
            num += rlf(sv, tag) + T[tagprev * 64 + tag];
            tagprev = tag;

            float am = alpha;
            #pragma unroll
            for (int m = 32; m; m >>= 1) am = fmaxf(am, __shfl_xor(am, m));
            float ea = __expf(alpha - am);
            float a0 = 0.f, a1 = 0.f, a2 = 0.f, a3 = 0.f;
            #pragma unroll
            for (int p = 0; p < 64; p += 4) {
                a0 = fmaf(rlf(ea, p + 0), Ec[p + 0], a0);
                a1 = fmaf(rlf(ea, p + 1), Ec[p + 1], a1);
                a2 = fmaf(rlf(ea, p + 2), Ec[p + 2], a2);
                a3 = fmaf(rlf(ea, p + 3), Ec[p + 3], a3);
            }
            alpha = am + __logf((a0 + a1) + (a2 + a3)) + sv;
        }

        num += end_trans[tagprev];
        float da = alpha + et;
        float dmx = da;
        #pragma unroll
        for (int m = 32; m; m >>= 1) dmx = fmaxf(dmx, __shfl_xor(dmx, m));
        float ds = __expf(da - dmx);
        #pragma unroll
        for (int m = 32; m; m >>= 1) ds += __shfl_xor(ds, m);
        float den = dmx + __logf(ds);
        if (lane == 0) rowterm[row] = num - den;
    } else {
        // ================= Viterbi max-only forward =================
        const float* srow = s_flat + (size_t)row * 16384;
        float* vrow = vsb + (size_t)row * 16384;

        float sv = srow[lane];
        float vs = start_trans[lane] + sv;
        float sv_pre = srow[64 + lane];

        for (int y = 1; y < len; ++y) {
            vrow[(y - 1) * 64 + lane] = vs;
            float svc = sv_pre;
            int ynext = (y + 1 < len) ? (y + 1) : (len - 1);
            sv_pre = srow[ynext * 64 + lane];

            float m0 = -3.4e38f, m1 = -3.4e38f, m2 = -3.4e38f, m3 = -3.4e38f;
            #pragma unroll
            for (int p = 0; p < 64; p += 8) {
                float t0 = rlf(vs, p + 0) + trans[(p + 0) * 64 + lane];
                float t1 = rlf(vs, p + 1) + trans[(p + 1) * 64 + lane];
                m0 = fmaxf(fmaxf(t0, t1), m0);
                float t2 = rlf(vs, p + 2) + trans[(p + 2) * 64 + lane];
                float t3 = rlf(vs, p + 3) + trans[(p + 3) * 64 + lane];
                m1 = fmaxf(fmaxf(t2, t3), m1);
                float t4 = rlf(vs, p + 4) + trans[(p + 4) * 64 + lane];
                float t5 = rlf(vs, p + 5) + trans[(p + 5) * 64 + lane];
                m2 = fmaxf(fmaxf(t4, t5), m2);
                float t6 = rlf(vs, p + 6) + trans[(p + 6) * 64 + lane];
                float t7 = rlf(vs, p + 7) + trans[(p + 7) * 64 + lane];
                m3 = fmaxf(fmaxf(t6, t7), m3);
            }
            vs = fmaxf(fmaxf(m0, m1), fmaxf(m2, m3)) + svc;
        }

        float fe = vs + end_trans[lane];
        float mx = fe;
        #pragma unroll
        for (int m = 32; m; m >>= 1) mx = fmaxf(mx, __shfl_xor(mx, m));
        unsigned long long msk = __ballot(fe == mx);
        int fi = (int)__builtin_ctzll(msk);

        if (lane == 0) decoded[(size_t)row * 256 + 255] = (float)fi;
    }
}

// ---------------------------------------------------------------------------
// Viterbi backward: recompute argmax per step from stored vs state.
// ---------------------------------------------------------------------------
__global__ __launch_bounds__(256)
void vitb_kernel(const float* __restrict__ vsb, const int* __restrict__ lenB,
                 const float* __restrict__ trans, float* __restrict__ decoded) {
    __shared__ float Tt[64][65];
    const int t = threadIdx.x;
    for (int i = t; i < 4096; i += 256) {
        int p = i >> 6, c = i & 63;
        Tt[c][p] = trans[i];
    }
    __syncthreads();

    const int lane = t & 63, wid = t >> 6;
    const int row = blockIdx.x * 4 + wid;
    const int len = lenB[row >> 8];
    const float* vrow = vsb + (size_t)row * 16384;
    float* drow = decoded + (size_t)row * 256;

    int cur = (int)drow[255];

    for (int y = len - 1 + lane; y < 255; y += 64) drow[y] = (float)cur;

    float v0 = vrow[(len - 2) * 64 + lane];
    float v1 = (len >= 3) ? vrow[(len - 3) * 64 + lane] : 0.f;

    for (int y = len - 2; y >= 0; --y) {
        float vy = v0;
        v0 = v1;
        v1 = (y >= 2) ? vrow[(y - 2) * 64 + lane] : 0.f;

        float tp = vy + Tt[cur][lane];
        float mx = tp;
        #pragma unroll
        for (int m = 32; m; m >>= 1) mx = fmaxf(mx, __shfl_xor(mx, m));
        unsigned long long msk = __ballot(tp == mx);
        cur = (int)__builtin_ctzll(msk);
        if (lane == 0) drow[y] = (float)cur;
    }
}

// ---------------------------------------------------------------------------
// FALLBACK path (small workspace): separate fwd + hist-based Viterbi.
// ---------------------------------------------------------------------------
__global__ __launch_bounds__(256, 4)
void fwd_kernel(const float* __restrict__ s_flat, const int* __restrict__ lenB,
                const int* __restrict__ maskI, const int* __restrict__ labels,
                const float* __restrict__ trans, const float* __restrict__ start_trans,
                const float* __restrict__ end_trans, float* __restrict__ rowterm) {
    __shared__ float T[4096];
    const int t = threadIdx.x;
    for (int i = t; i < 4096; i += 256) T[i] = trans[i];
    __syncthreads();

    const int lane = t & 63, wid = t >> 6;
    const int row = blockIdx.x * 4 + wid;
    if (maskI[row] == 0) {
        if (lane == 0) rowterm[row] = 0.f;
        return;
    }
    const int len = lenB[row >> 8];
    const float* srow = s_flat + (size_t)row * 16384;
    const int* lrow = labels + (size_t)row * 256;

    float Ec[64];
    #pragma unroll
    for (int p = 0; p < 64; ++p) Ec[p] = __expf(T[p * 64 + lane]);

    const float et = end_trans[lane];

    float sv = srow[lane];
    int tagprev = lrow[0];
    float num = start_trans[tagprev] + rlf(sv, tagprev);
    float alpha = start_trans[lane] + sv;
    float sv_pre = srow[64 + lane];

    for (int y = 1; y < len; ++y) {
        sv = sv_pre;
        int ynext = (y + 1 < len) ? (y + 1) : (len - 1);
        sv_pre = srow[ynext * 64 + lane];

        const int tag = lrow[y];
        num += rlf(sv, tag) + T[tagprev * 64 + tag];
        tagprev = tag;

        float am = alpha;
        #pragma unroll
        for (int m = 32; m; m >>= 1) am = fmaxf(am, __shfl_xor(am, m));
        float ea = __expf(alpha - am);
        float a0 = 0.f, a1 = 0.f, a2 = 0.f, a3 = 0.f;
        #pragma unroll
        for (int p = 0; p < 64; p += 4) {
            a0 = fmaf(rlf(ea, p + 0), Ec[p + 0], a0);
            a1 = fmaf(rlf(ea, p + 1), Ec[p + 1], a1);
            a2 = fmaf(rlf(ea, p + 2), Ec[p + 2], a2);
            a3 = fmaf(rlf(ea, p + 3), Ec[p + 3], a3);
        }
        alpha = am + __logf((a0 + a1) + (a2 + a3)) + sv;
    }

    num += end_trans[tagprev];
    float da = alpha + et;
    float dmx = da;
    #pragma unroll
    for (int m = 32; m; m >>= 1) dmx = fmaxf(dmx, __shfl_xor(dmx, m));
    float ds = __expf(da - dmx);
    #pragma unroll
    for (int m = 32; m; m >>= 1) ds += __shfl_xor(ds, m);
    float den = dmx + __logf(ds);
    if (lane == 0) rowterm[row] = num - den;
}

__global__ __launch_bounds__(256, 3)
void vit_kernel(const float* __restrict__ s_flat, const int* __restrict__ lenB,
                const float* __restrict__ trans, const float* __restrict__ start_trans,
                const float* __restrict__ end_trans, unsigned char* __restrict__ hist,
                float* __restrict__ decoded) {
    const int t = threadIdx.x;
    const int lane = t & 63, wid = t >> 6;
    const int row = blockIdx.x * 4 + wid;
    const int len = lenB[row >> 8];
    const float* srow = s_flat + (size_t)row * 16384;
    unsigned char* hrow = hist + (size_t)row * 16320;

    float sv = srow[lane];
    float vs = start_trans[lane] + sv;
    float sv_pre = srow[64 + lane];

    for (int y = 1; y < len; ++y) {
        sv = sv_pre;
        int ynext = (y + 1 < len) ? (y + 1) : (len - 1);
        sv_pre = srow[ynext * 64 + lane];

        float b0 = -3.4e38f, b1 = -3.4e38f, b2 = -3.4e38f, b3 = -3.4e38f;
        int i0 = 0, i1 = 1, i2 = 2, i3 = 3;
        #pragma unroll
        for (int p = 0; p < 64; p += 4) {
            float t0 = rlf(vs, p + 0) + trans[(p + 0) * 64 + lane]; if (t0 > b0) { b0 = t0; i0 = p + 0; }
            float t1 = rlf(vs, p + 1) + trans[(p + 1) * 64 + lane]; if (t1 > b1) { b1 = t1; i1 = p + 1; }
            float t2 = rlf(vs, p + 2) + trans[(p + 2) * 64 + lane]; if (t2 > b2) { b2 = t2; i2 = p + 2; }
            float t3 = rlf(vs, p + 3) + trans[(p + 3) * 64 + lane]; if (t3 > b3) { b3 = t3; i3 = p + 3; }
        }
        bool c;
        c = (b1 > b0) || (b1 == b0 && i1 < i0);
        float bA = c ? b1 : b0; int iA = c ? i1 : i0;
        c = (b3 > b2) || (b3 == b2 && i3 < i2);
        float bB = c ? b3 : b2; int iB = c ? i3 : i2;
        c = (bB > bA) || (bB == bA && iB < iA);
        float bbv = c ? bB : bA; int bi = c ? iB : iA;

        hrow[(size_t)(y - 1) * 64 + lane] = (unsigned char)bi;
        vs = bbv + sv;
    }

    float fv = vs + end_trans[lane]; int fi = lane;
    #pragma unroll
    for (int m = 32; m; m >>= 1) {
        float ov = __shfl_xor(fv, m);
        int oi = __shfl_xor(fi, m);
        bool cc = (ov > fv) || (ov == fv && oi < fi);
        fv = cc ? ov : fv; fi = cc ? oi : fi;
    }

    if (lane == 0) decoded[(size_t)row * 256 + 255] = (float)fi;
}

__global__ __launch_bounds__(256)
void backtrack_kernel(const unsigned char* __restrict__ hist, const int* __restrict__ lenB,
                      float* __restrict__ decoded) {
    const int lane = threadIdx.x & 63, wid = threadIdx.x >> 6;
    const int row = blockIdx.x * 4 + wid;
    const int len = lenB[row >> 8];
    const unsigned char* hrow = hist + (size_t)row * 16320;
    float* drow = decoded + (size_t)row * 256;

    int cur = (int)drow[255];
    for (int y = len - 1 + lane; y < 255; y += 64) drow[y] = (float)cur;

    int t0 = len - 2;
    int c0 = (int)hrow[(t0 - 0) * 64 + lane];
    int c1 = (int)hrow[(t0 - 1) * 64 + lane];
    int c2 = (int)hrow[(t0 - 2) * 64 + lane];
    int c3 = (int)hrow[(t0 - 3) * 64 + lane];

    for (int y = t0; y >= 0; y -= 4) {
        int yn = y - 4;
        int n0 = 0, n1 = 0, n2 = 0, n3 = 0;
        if (yn - 0 >= 0) n0 = (int)hrow[(yn - 0) * 64 + lane];
        if (yn - 1 >= 0) n1 = (int)hrow[(yn - 1) * 64 + lane];
        if (yn - 2 >= 0) n2 = (int)hrow[(yn - 2) * 64 + lane];
        if (yn - 3 >= 0) n3 = (int)hrow[(yn - 3) * 64 + lane];

        cur = rli(c0, cur);
        if (lane == 0) drow[y] = (float)cur;
        if (y - 1 >= 0) { cur = rli(c1, cur); if (lane == 0) drow[y - 1] = (float)cur; }
        if (y - 2 >= 0) { cur = rli(c2, cur); if (lane == 0) drow[y - 2] = (float)cur; }
        if (y - 3 >= 0) { cur = rli(c3, cur); if (lane == 0) drow[y - 3] = (float)cur; }

        c0 = n0; c1 = n1; c2 = n2; c3 = n3;
    }
}

__global__ void loss_kernel(const float* __restrict__ rowterm, float* __restrict__ out) {
    __shared__ float wsum[4];
    int t = threadIdx.x;
    float s = 0.f;
    for (int i = t; i < 4096; i += 256) s += rowterm[i];
    #pragma unroll
    for (int m = 32; m; m >>= 1) s += __shfl_xor(s, m);
    if ((t & 63) == 0) wsum[t >> 6] = s;
    __syncthreads();
    if (t == 0) out[0] = -(wsum[0] + wsum[1] + wsum[2] + wsum[3]);
}

extern "C" void kernel_launch(void* const* d_in, const int* in_sizes, int n_in,
                              void* d_out, int out_size, void* d_ws, size_t ws_size,
                              hipStream_t stream) {
    const float* input  = (const float*)d_in[0];
    const void*  mraw   = d_in[1];
    const int*   labels = (const int*)d_in[2];
    const float* Wh_in  = (const float*)d_in[3];
    const float* bh     = (const float*)d_in[4];
    const float* Wd_in  = (const float*)d_in[5];
    const float* bd     = (const float*)d_in[6];
    const float* Wbil   = (const float*)d_in[7];
    const float* stt    = (const float*)d_in[8];
    const float* trans  = (const float*)d_in[9];
    const float* ett    = (const float*)d_in[10];

    float* out     = (float*)d_out;
    float* s_flat  = out + 1;
    float* decoded = out + 1 + (size_t)67108864;

    char* ws = (char*)d_ws;
    size_t off = 0;
    unsigned short* h1h = (unsigned short*)(ws + off); off += (size_t)4096 * 304 * 2;
    unsigned short* h1l = (unsigned short*)(ws + off); off += (size_t)4096 * 304 * 2;
    unsigned short* d1h = (unsigned short*)(ws + off); off += (size_t)4096 * 304 * 2;
    unsigned short* d1l = (unsigned short*)(ws + off); off += (size_t)4096 * 304 * 2;
    unsigned short* Wbh = (unsigned short*)(ws + off); off += (size_t)19456 * 304 * 2;
    unsigned short* Wbl = (unsigned short*)(ws + off); off += (size_t)19456 * 304 * 2;
    int* maskI = (int*)(ws + off); off += 16384;
    int* lenB  = (int*)(ws + off); off += 256;
    int* zbuf  = (int*)(ws + off); off += 256;
    float* rowterm = (float*)(ws + off); off += 16384;

    const size_t vsb_bytes = (size_t)4096 * 16384 * 4;
    const size_t hist_bytes = (size_t)4096 * 16320;
    const size_t perb = (size_t)256 * 19456 * 2 * 2;

    bool newpath = (ws_size >= off + vsb_bytes + perb);
    float* vsb = nullptr;
    unsigned char* hist = nullptr;
    if (newpath) { vsb  = (float*)(ws + off); off += vsb_bytes; }
    else         { hist = (unsigned char*)(ws + off); off += hist_bytes; }

    unsigned short* Uh = (unsigned short*)(ws + off);
    size_t avail = (ws_size > off) ? ws_size - off : 0;
    int CB = (int)(avail / perb);
    if (CB < 1) CB = 1;
    if (CB > 16) CB = 16;
    unsigned short* Ul = Uh + (size_t)CB * 256 * 19456;

    mask_cvt_kernel<<<16, 256, 0, stream>>>(mraw, maskI, lenB, zbuf);
    wsplit_kernel<<<dim3(64, 19), 256, 0, stream>>>(Wbil, Wbh, Wbl);
    mlp_kernel<<<dim3(32, 3, 2), 256, 0, stream>>>(input, Wh_in, bh, Wd_in, bd,
                                                   h1h, h1l, d1h, d1l);

    for (int c0 = 0; c0 < 16; c0 += CB) {
        int cb = (CB < 16 - c0) ? CB : (16 - c0);
        gemm_mfma<1><<<dim3(cb * 2, 152), 256, 0, stream>>>(
            d1h, d1l, Wbh, Wbl, nullptr, Uh, Ul, (const unsigned short*)zbuf, c0);
        gemm_mfma<2><<<dim3(2, 128, cb), 256, 0, stream>>>(
            h1h, h1l, Uh, Ul, s_flat, nullptr, nullptr, (const unsigned short*)zbuf, c0);
    }

    if (newpath) {
        crfpar_kernel<<<dim3(1024, 2), 256, 0, stream>>>(
            s_flat, lenB, maskI, labels, trans, stt, ett, rowterm, vsb, decoded);
        vitb_kernel<<<1024, 256, 0, stream>>>(vsb, lenB, trans, decoded);
    } else {
        fwd_kernel<<<1024, 256, 0, stream>>>(s_flat, lenB, maskI, labels, trans,
                                             stt, ett, rowterm);
        vit_kernel<<<1024, 256, 0, stream>>>(s_flat, lenB, trans, stt, ett, hist, decoded);
        backtrack_kernel<<<1024, 256, 0, stream>>>(hist, lenB, decoded);
    }
    loss_kernel<<<1, 256, 0, stream>>>(rowterm, out);
}